// Round 5
// baseline (650.596 us; speedup 1.0000x reference)
//
#include <hip/hip_runtime.h>
#include <math.h>

#define L 2048
#define B 8
#define D 1024
#define ND 16
#define BD (B*D)
#define ROWS 8
#define NGRP (L/ROWS)   // 256 groups of 8 rows
#define PF 3            // groups in flight ahead of compute

__device__ __forceinline__ float sigmoid_precise(float v) {
    return 1.0f / (1.0f + expf(-v));
}

// Shared body. DIR = 0: forward (causal, coefficient rows [0,D)), writes
// residual + causal part. DIR = 1: backward (anti-causal, rows [D,2D)),
// adds its part and applies silu in place.
template<int DIR>
__device__ __forceinline__ void ema_scan_body(
    const float* __restrict__ x, const float* __restrict__ damp,
    const float* __restrict__ decay, const float* __restrict__ ema,
    const float* __restrict__ proj, const float* __restrict__ rw,
    const int* __restrict__ mask, float* __restrict__ out)
{
    const int t  = threadIdx.x;   // 64 = 16 channels x 4 mode-groups
    const int ng = t & 3;         // mode group: modes ng*4 .. ng*4+3
    const int dl = t >> 2;        // 0..15
    const int d  = blockIdx.x * 16 + dl;
    const int b  = blockIdx.y;
    const int row = (DIR == 0) ? d : (d + D);

    float q[4], c[4];
#pragma unroll
    for (int k = 0; k < 4; ++k) {
        const int n   = ng * 4 + k;
        const int idx = row * ND + n;
        const float p  = sigmoid_precise(damp[idx]);
        const float sd = sigmoid_precise(decay[idx]);
        q[k] = 1.0f - p * sd;
        c[k] = p * ema[idx] * proj[idx] * 0.25f;  // 1/sqrt(16)
    }
    const float w = rw[d];
    const float* xp = x + (size_t)b * D + d;
    float*       op = out + (size_t)b * D + d;
    const int*   mp = mask + (size_t)b * L;

    float s0 = 0.f, s1 = 0.f, s2 = 0.f, s3 = 0.f;

    // software pipeline: xbuf[0] = current group, xbuf[1..PF] = in flight
    float xbuf[PF + 1][ROWS];
    float mbuf[PF + 1][ROWS];
#pragma unroll
    for (int s = 0; s <= PF; ++s)
#pragma unroll
        for (int u = 0; u < ROWS; ++u) { xbuf[s][u] = 0.f; mbuf[s][u] = 0.f; }

    // preload groups 0..PF-1
#pragma unroll
    for (int s = 0; s < PF; ++s) {
#pragma unroll
        for (int u = 0; u < ROWS; ++u) {
            const int r = s * ROWS + u;
            const int j = (DIR == 0) ? r : (L - 1 - r);
            xbuf[s][u] = xp[(size_t)j * BD];
            mbuf[s][u] = (float)mp[j];
        }
    }

    for (int g = 0; g < NGRP; ++g) {
        // issue loads for group g+PF (keeps PF*ROWS loads in flight)
        if (g + PF < NGRP) {
            const int base = (g + PF) * ROWS;
#pragma unroll
            for (int u = 0; u < ROWS; ++u) {
                const int j = (DIR == 0) ? (base + u) : (L - 1 - (base + u));
                xbuf[PF][u] = xp[(size_t)j * BD];
                mbuf[PF][u] = (float)mp[j];
            }
        }

        float acc[ROWS];
#pragma unroll
        for (int u = 0; u < ROWS; ++u) {
            const float xm = xbuf[0][u] * mbuf[0][u];
            s0 = fmaf(q[0], s0, xm);
            s1 = fmaf(q[1], s1, xm);
            s2 = fmaf(q[2], s2, xm);
            s3 = fmaf(q[3], s3, xm);
            const float a01 = fmaf(c[1], s1, c[0] * s0);
            const float a23 = fmaf(c[3], s3, c[2] * s2);
            acc[u] = a01 + a23;
        }
        // reduce across the 4 mode-groups (lane bits 0..1)
#pragma unroll
        for (int u = 0; u < ROWS; ++u) acc[u] += __shfl_xor(acc[u], 1);
#pragma unroll
        for (int u = 0; u < ROWS; ++u) acc[u] += __shfl_xor(acc[u], 2);

        if (ng == 0) {
            const int base = g * ROWS;
#pragma unroll
            for (int u = 0; u < ROWS; ++u) {
                const int j = (DIR == 0) ? (base + u) : (L - 1 - (base + u));
                const size_t oi = (size_t)j * BD;
                if (DIR == 0) {
                    // residual uses UNMASKED input
                    op[oi] = fmaf(xbuf[0][u], w, acc[u]);
                } else {
                    const float v = op[oi] + acc[u];
                    op[oi] = v / (1.0f + expf(-v));  // silu
                }
            }
        }

        // rotate pipeline
#pragma unroll
        for (int s = 0; s < PF; ++s)
#pragma unroll
            for (int u = 0; u < ROWS; ++u) {
                xbuf[s][u] = xbuf[s + 1][u];
                mbuf[s][u] = mbuf[s + 1][u];
            }
    }
}

__global__ __launch_bounds__(64) void ema_fwd_kernel(
    const float* __restrict__ x, const float* __restrict__ damp,
    const float* __restrict__ decay, const float* __restrict__ ema,
    const float* __restrict__ proj, const float* __restrict__ rw,
    const int* __restrict__ mask, float* __restrict__ out)
{
    ema_scan_body<0>(x, damp, decay, ema, proj, rw, mask, out);
}

__global__ __launch_bounds__(64) void ema_bwd_kernel(
    const float* __restrict__ x, const float* __restrict__ damp,
    const float* __restrict__ decay, const float* __restrict__ ema,
    const float* __restrict__ proj, const float* __restrict__ rw,
    const int* __restrict__ mask, float* __restrict__ out)
{
    ema_scan_body<1>(x, damp, decay, ema, proj, rw, mask, out);
}

extern "C" void kernel_launch(void* const* d_in, const int* in_sizes, int n_in,
                              void* d_out, int out_size, void* d_ws, size_t ws_size,
                              hipStream_t stream) {
    const float* x     = (const float*)d_in[0];
    const float* damp  = (const float*)d_in[1];
    const float* decay = (const float*)d_in[2];
    const float* ema   = (const float*)d_in[3];
    const float* proj  = (const float*)d_in[4];
    const float* rw    = (const float*)d_in[5];
    const int*   mask  = (const int*)d_in[6];
    float* out = (float*)d_out;

    dim3 grid(D / 16, B);
    dim3 block(64);
    ema_fwd_kernel<<<grid, block, 0, stream>>>(x, damp, decay, ema, proj, rw, mask, out);
    ema_bwd_kernel<<<grid, block, 0, stream>>>(x, damp, decay, ema, proj, rw, mask, out);
}

// Round 6
// 287.419 us; speedup vs baseline: 2.2636x; 2.2636x over previous
//
#include <hip/hip_runtime.h>
#include <math.h>

#define L 2048
#define B 8
#define D 1024
#define ND 16
#define BD (B*D)
#define CK 128              // chunk length
#define NC (L/CK)           // 16 chunks
#define SZ (B*NC*D*ND)      // per-direction state elements (2,097,152)

__device__ __forceinline__ float sigmoid_precise(float v) {
    return 1.0f / (1.0f + expf(-v));
}

// ---------------- Phase A: per-chunk local states (both directions) ----------
// fwd E  = state after scanning chunk forward from 0   (modes of row d)
// bwd Eh = state after scanning chunk backward from 0  (modes of row d+D),
//          accumulated in the same forward loop as Eh += q2^(j-j0) * xm.
__global__ __launch_bounds__(64) void ema_summary_kernel(
    const float* __restrict__ x, const float* __restrict__ damp,
    const float* __restrict__ decay, const int* __restrict__ mask,
    float* __restrict__ fwdS, float* __restrict__ bwdS)
{
    const int t  = threadIdx.x;
    const int ng = t & 3;
    const int dl = t >> 2;
    const int d  = blockIdx.x * 16 + dl;
    const int b  = blockIdx.y;
    const int ch = blockIdx.z;

    const float4 dp1 = reinterpret_cast<const float4*>(damp)[d * 4 + ng];
    const float4 dc1 = reinterpret_cast<const float4*>(decay)[d * 4 + ng];
    const float4 dp2 = reinterpret_cast<const float4*>(damp)[(d + D) * 4 + ng];
    const float4 dc2 = reinterpret_cast<const float4*>(decay)[(d + D) * 4 + ng];
    float q1[4], q2[4];
    q1[0] = 1.f - sigmoid_precise(dp1.x) * sigmoid_precise(dc1.x);
    q1[1] = 1.f - sigmoid_precise(dp1.y) * sigmoid_precise(dc1.y);
    q1[2] = 1.f - sigmoid_precise(dp1.z) * sigmoid_precise(dc1.z);
    q1[3] = 1.f - sigmoid_precise(dp1.w) * sigmoid_precise(dc1.w);
    q2[0] = 1.f - sigmoid_precise(dp2.x) * sigmoid_precise(dc2.x);
    q2[1] = 1.f - sigmoid_precise(dp2.y) * sigmoid_precise(dc2.y);
    q2[2] = 1.f - sigmoid_precise(dp2.z) * sigmoid_precise(dc2.z);
    q2[3] = 1.f - sigmoid_precise(dp2.w) * sigmoid_precise(dc2.w);

    const float* xp = x + (size_t)b * D + d;
    const int*   mp = mask + (size_t)b * L;
    const int j0 = ch * CK;

    float E[4]  = {0.f, 0.f, 0.f, 0.f};
    float Eh[4] = {0.f, 0.f, 0.f, 0.f};
    float w2[4] = {1.f, 1.f, 1.f, 1.f};

    for (int u = 0; u < CK; u += 4) {
        float xv[4], mf[4];
#pragma unroll
        for (int v = 0; v < 4; ++v) {
            const int j = j0 + u + v;
            xv[v] = xp[(size_t)j * BD];
            mf[v] = (float)mp[j];
        }
#pragma unroll
        for (int v = 0; v < 4; ++v) {
            const float xm = xv[v] * mf[v];
#pragma unroll
            for (int k = 0; k < 4; ++k) {
                E[k]  = fmaf(q1[k], E[k], xm);
                Eh[k] = fmaf(w2[k], xm, Eh[k]);
                w2[k] *= q2[k];
            }
        }
    }
    const int si = ((b * NC + ch) * D + d) * 4 + ng;   // float4 index
    reinterpret_cast<float4*>(fwdS)[si] = make_float4(E[0], E[1], E[2], E[3]);
    reinterpret_cast<float4*>(bwdS)[si] = make_float4(Eh[0], Eh[1], Eh[2], Eh[3]);
}

// ---------------- Phase B: prefix across chunks (in-place -> entry states) ---
__global__ __launch_bounds__(64) void ema_prefix_kernel(
    const float* __restrict__ damp, const float* __restrict__ decay,
    float* __restrict__ fwdS, float* __restrict__ bwdS)
{
    const int tid = blockIdx.x * 64 + threadIdx.x;   // B*D*4 total
    const int ng = tid & 3;
    const int d  = (tid >> 2) & (D - 1);
    const int b  = tid >> 12;

    float4* f4 = reinterpret_cast<float4*>(fwdS);
    float4* b4 = reinterpret_cast<float4*>(bwdS);

    // forward chain (modes of row d)
    {
        const float4 dp = reinterpret_cast<const float4*>(damp)[d * 4 + ng];
        const float4 dc = reinterpret_cast<const float4*>(decay)[d * 4 + ng];
        float qp[4];
        qp[0] = 1.f - sigmoid_precise(dp.x) * sigmoid_precise(dc.x);
        qp[1] = 1.f - sigmoid_precise(dp.y) * sigmoid_precise(dc.y);
        qp[2] = 1.f - sigmoid_precise(dp.z) * sigmoid_precise(dc.z);
        qp[3] = 1.f - sigmoid_precise(dp.w) * sigmoid_precise(dc.w);
#pragma unroll
        for (int s = 0; s < 7; ++s) { qp[0]*=qp[0]; qp[1]*=qp[1]; qp[2]*=qp[2]; qp[3]*=qp[3]; }  // q^128
        float F[4] = {0.f, 0.f, 0.f, 0.f};
        for (int i = 0; i < NC; ++i) {
            const int si = ((b * NC + i) * D + d) * 4 + ng;
            const float4 E = f4[si];
            f4[si] = make_float4(F[0], F[1], F[2], F[3]);   // entry state for chunk i
            F[0] = fmaf(qp[0], F[0], E.x);
            F[1] = fmaf(qp[1], F[1], E.y);
            F[2] = fmaf(qp[2], F[2], E.z);
            F[3] = fmaf(qp[3], F[3], E.w);
        }
    }
    // backward chain (modes of row d+D)
    {
        const float4 dp = reinterpret_cast<const float4*>(damp)[(d + D) * 4 + ng];
        const float4 dc = reinterpret_cast<const float4*>(decay)[(d + D) * 4 + ng];
        float qp[4];
        qp[0] = 1.f - sigmoid_precise(dp.x) * sigmoid_precise(dc.x);
        qp[1] = 1.f - sigmoid_precise(dp.y) * sigmoid_precise(dc.y);
        qp[2] = 1.f - sigmoid_precise(dp.z) * sigmoid_precise(dc.z);
        qp[3] = 1.f - sigmoid_precise(dp.w) * sigmoid_precise(dc.w);
#pragma unroll
        for (int s = 0; s < 7; ++s) { qp[0]*=qp[0]; qp[1]*=qp[1]; qp[2]*=qp[2]; qp[3]*=qp[3]; }
        float G[4] = {0.f, 0.f, 0.f, 0.f};
        for (int i = NC - 1; i >= 0; --i) {
            const int si = ((b * NC + i) * D + d) * 4 + ng;
            const float4 E = b4[si];
            b4[si] = make_float4(G[0], G[1], G[2], G[3]);   // entry state for chunk i
            G[0] = fmaf(qp[0], G[0], E.x);
            G[1] = fmaf(qp[1], G[1], E.y);
            G[2] = fmaf(qp[2], G[2], E.z);
            G[3] = fmaf(qp[3], G[3], E.w);
        }
    }
}

// ---------------- Phase C: apply (both directions + residual + silu) ---------
__global__ __launch_bounds__(64) void ema_apply_kernel(
    const float* __restrict__ x, const float* __restrict__ damp,
    const float* __restrict__ decay, const float* __restrict__ ema,
    const float* __restrict__ proj, const float* __restrict__ rw,
    const int* __restrict__ mask,
    const float* __restrict__ fwdS, const float* __restrict__ bwdS,
    float* __restrict__ out)
{
    __shared__ float tile[CK * 16];   // fwd contribution + residual, per (row, channel)

    const int t  = threadIdx.x;
    const int ng = t & 3;
    const int dl = t >> 2;
    const int d  = blockIdx.x * 16 + dl;
    const int b  = blockIdx.y;
    const int ch = blockIdx.z;

    float q1[4], c1[4], q2[4], c2[4];
    {
        const float4 dp = reinterpret_cast<const float4*>(damp)[d * 4 + ng];
        const float4 dc = reinterpret_cast<const float4*>(decay)[d * 4 + ng];
        const float4 em = reinterpret_cast<const float4*>(ema)[d * 4 + ng];
        const float4 pj = reinterpret_cast<const float4*>(proj)[d * 4 + ng];
        const float p0 = sigmoid_precise(dp.x), p1 = sigmoid_precise(dp.y),
                    p2 = sigmoid_precise(dp.z), p3 = sigmoid_precise(dp.w);
        q1[0] = 1.f - p0 * sigmoid_precise(dc.x);
        q1[1] = 1.f - p1 * sigmoid_precise(dc.y);
        q1[2] = 1.f - p2 * sigmoid_precise(dc.z);
        q1[3] = 1.f - p3 * sigmoid_precise(dc.w);
        c1[0] = p0 * em.x * pj.x * 0.25f;
        c1[1] = p1 * em.y * pj.y * 0.25f;
        c1[2] = p2 * em.z * pj.z * 0.25f;
        c1[3] = p3 * em.w * pj.w * 0.25f;
    }
    {
        const float4 dp = reinterpret_cast<const float4*>(damp)[(d + D) * 4 + ng];
        const float4 dc = reinterpret_cast<const float4*>(decay)[(d + D) * 4 + ng];
        const float4 em = reinterpret_cast<const float4*>(ema)[(d + D) * 4 + ng];
        const float4 pj = reinterpret_cast<const float4*>(proj)[(d + D) * 4 + ng];
        const float p0 = sigmoid_precise(dp.x), p1 = sigmoid_precise(dp.y),
                    p2 = sigmoid_precise(dp.z), p3 = sigmoid_precise(dp.w);
        q2[0] = 1.f - p0 * sigmoid_precise(dc.x);
        q2[1] = 1.f - p1 * sigmoid_precise(dc.y);
        q2[2] = 1.f - p2 * sigmoid_precise(dc.z);
        q2[3] = 1.f - p3 * sigmoid_precise(dc.w);
        c2[0] = p0 * em.x * pj.x * 0.25f;
        c2[1] = p1 * em.y * pj.y * 0.25f;
        c2[2] = p2 * em.z * pj.z * 0.25f;
        c2[3] = p3 * em.w * pj.w * 0.25f;
    }
    const float w = rw[d];
    const float* xp = x + (size_t)b * D + d;
    float*       op = out + (size_t)b * D + d;
    const int*   mp = mask + (size_t)b * L;
    const int j0 = ch * CK;
    const int si = ((b * NC + ch) * D + d) * 4 + ng;

    // entry states
    const float4 sf = reinterpret_cast<const float4*>(fwdS)[si];
    const float4 sb = reinterpret_cast<const float4*>(bwdS)[si];
    float s[4] = {sf.x, sf.y, sf.z, sf.w};
    float tt[4] = {sb.x, sb.y, sb.z, sb.w};

    // forward sweep: residual + causal into LDS tile
    for (int u = 0; u < CK; u += 4) {
        float xv[4], mf[4];
#pragma unroll
        for (int v = 0; v < 4; ++v) {
            const int j = j0 + u + v;
            xv[v] = xp[(size_t)j * BD];
            mf[v] = (float)mp[j];
        }
#pragma unroll
        for (int v = 0; v < 4; ++v) {
            const float xm = xv[v] * mf[v];
            s[0] = fmaf(q1[0], s[0], xm);
            s[1] = fmaf(q1[1], s[1], xm);
            s[2] = fmaf(q1[2], s[2], xm);
            s[3] = fmaf(q1[3], s[3], xm);
            float acc = fmaf(c1[1], s[1], c1[0] * s[0]) + fmaf(c1[3], s[3], c1[2] * s[2]);
            acc += __shfl_xor(acc, 1);
            acc += __shfl_xor(acc, 2);
            if (ng == 0) tile[(u + v) * 16 + dl] = fmaf(xv[v], w, acc);
        }
    }

    // backward sweep: anti-causal + combine + silu + store
    for (int u = CK - 4; u >= 0; u -= 4) {
        float xv[4], mf[4];
#pragma unroll
        for (int v = 0; v < 4; ++v) {
            const int j = j0 + u + v;
            xv[v] = xp[(size_t)j * BD];
            mf[v] = (float)mp[j];
        }
#pragma unroll
        for (int v = 3; v >= 0; --v) {
            const float xm = xv[v] * mf[v];
            tt[0] = fmaf(q2[0], tt[0], xm);
            tt[1] = fmaf(q2[1], tt[1], xm);
            tt[2] = fmaf(q2[2], tt[2], xm);
            tt[3] = fmaf(q2[3], tt[3], xm);
            float acc = fmaf(c2[1], tt[1], c2[0] * tt[0]) + fmaf(c2[3], tt[3], c2[2] * tt[2]);
            acc += __shfl_xor(acc, 1);
            acc += __shfl_xor(acc, 2);
            if (ng == 0) {
                const float val = tile[(u + v) * 16 + dl] + acc;
                op[(size_t)(j0 + u + v) * BD] = val / (1.0f + expf(-val));
            }
        }
    }
}

// ---------------- Fallback: validated round-5 single-pass scans --------------
template<int DIR>
__device__ __forceinline__ void ema_scan_body(
    const float* __restrict__ x, const float* __restrict__ damp,
    const float* __restrict__ decay, const float* __restrict__ ema,
    const float* __restrict__ proj, const float* __restrict__ rw,
    const int* __restrict__ mask, float* __restrict__ out)
{
    const int t  = threadIdx.x;
    const int ng = t & 3;
    const int dl = t >> 2;
    const int d  = blockIdx.x * 16 + dl;
    const int b  = blockIdx.y;
    const int row = (DIR == 0) ? d : (d + D);

    float q[4], c[4];
#pragma unroll
    for (int k = 0; k < 4; ++k) {
        const int idx = row * ND + ng * 4 + k;
        const float p  = sigmoid_precise(damp[idx]);
        const float sd = sigmoid_precise(decay[idx]);
        q[k] = 1.0f - p * sd;
        c[k] = p * ema[idx] * proj[idx] * 0.25f;
    }
    const float w = rw[d];
    const float* xp = x + (size_t)b * D + d;
    float*       op = out + (size_t)b * D + d;
    const int*   mp = mask + (size_t)b * L;
    float s0 = 0.f, s1 = 0.f, s2 = 0.f, s3 = 0.f;

    for (int jj = 0; jj < L; jj += 4) {
        float xv[4], mf[4];
#pragma unroll
        for (int u = 0; u < 4; ++u) {
            const int j = (DIR == 0) ? (jj + u) : (L - 1 - (jj + u));
            xv[u] = xp[(size_t)j * BD];
            mf[u] = (float)mp[j];
        }
        float acc[4];
#pragma unroll
        for (int u = 0; u < 4; ++u) {
            const float xm = xv[u] * mf[u];
            s0 = fmaf(q[0], s0, xm);
            s1 = fmaf(q[1], s1, xm);
            s2 = fmaf(q[2], s2, xm);
            s3 = fmaf(q[3], s3, xm);
            acc[u] = fmaf(c[1], s1, c[0] * s0) + fmaf(c[3], s3, c[2] * s2);
        }
#pragma unroll
        for (int u = 0; u < 4; ++u) acc[u] += __shfl_xor(acc[u], 1);
#pragma unroll
        for (int u = 0; u < 4; ++u) acc[u] += __shfl_xor(acc[u], 2);
        if (ng == 0) {
#pragma unroll
            for (int u = 0; u < 4; ++u) {
                const int j = (DIR == 0) ? (jj + u) : (L - 1 - (jj + u));
                const size_t oi = (size_t)j * BD;
                if (DIR == 0) op[oi] = fmaf(xv[u], w, acc[u]);
                else { const float v = op[oi] + acc[u]; op[oi] = v / (1.0f + expf(-v)); }
            }
        }
    }
}

__global__ __launch_bounds__(64) void ema_fwd_kernel(
    const float* __restrict__ x, const float* __restrict__ damp,
    const float* __restrict__ decay, const float* __restrict__ ema,
    const float* __restrict__ proj, const float* __restrict__ rw,
    const int* __restrict__ mask, float* __restrict__ out)
{ ema_scan_body<0>(x, damp, decay, ema, proj, rw, mask, out); }

__global__ __launch_bounds__(64) void ema_bwd_kernel(
    const float* __restrict__ x, const float* __restrict__ damp,
    const float* __restrict__ decay, const float* __restrict__ ema,
    const float* __restrict__ proj, const float* __restrict__ rw,
    const int* __restrict__ mask, float* __restrict__ out)
{ ema_scan_body<1>(x, damp, decay, ema, proj, rw, mask, out); }

extern "C" void kernel_launch(void* const* d_in, const int* in_sizes, int n_in,
                              void* d_out, int out_size, void* d_ws, size_t ws_size,
                              hipStream_t stream) {
    const float* x     = (const float*)d_in[0];
    const float* damp  = (const float*)d_in[1];
    const float* decay = (const float*)d_in[2];
    const float* ema   = (const float*)d_in[3];
    const float* proj  = (const float*)d_in[4];
    const float* rw    = (const float*)d_in[5];
    const int*   mask  = (const int*)d_in[6];
    float* out = (float*)d_out;

    const size_t need = (size_t)2 * SZ * sizeof(float);   // 16 MiB
    if (ws_size >= need) {
        float* fwdS = (float*)d_ws;
        float* bwdS = fwdS + SZ;
        dim3 blk(64);
        dim3 gA(D / 16, B, NC);
        ema_summary_kernel<<<gA, blk, 0, stream>>>(x, damp, decay, mask, fwdS, bwdS);
        ema_prefix_kernel<<<dim3(B * D * 4 / 64), blk, 0, stream>>>(damp, decay, fwdS, bwdS);
        ema_apply_kernel<<<gA, blk, 0, stream>>>(x, damp, decay, ema, proj, rw, mask,
                                                 fwdS, bwdS, out);
    } else {
        dim3 grid(D / 16, B);
        dim3 block(64);
        ema_fwd_kernel<<<grid, block, 0, stream>>>(x, damp, decay, ema, proj, rw, mask, out);
        ema_bwd_kernel<<<grid, block, 0, stream>>>(x, damp, decay, ema, proj, rw, mask, out);
    }
}